// Round 4
// baseline (912.474 us; speedup 1.0000x reference)
//
#include <hip/hip_runtime.h>
#include <hip/hip_fp16.h>
#include <math.h>

#define EMB_DIM 256
#define NUM_EMB 2048
#define N_ROWS  65536            // 64*32*32
#define N_ELEM  16777216         // N_ROWS * EMB_DIM
#define EPS_GAP 5e-4f
#define DBIAS   48.0f            // distances biased into [32,64) binade

// ---- workspace layout (in 4-byte elements), ~5.8 MB (same footprint as R3) ----
#define IDX_OFF    0             // int[65536]
#define ESQ_OFF    65536         // float[2048]
#define EBIAS_OFF  67584         // float[2048]
#define HIST_OFF   69632        // int[2048]      -- zero-memset start
#define BKT_OFF    71680        // float[256]
#define CNT_OFF    71936        // int[64]        -- zero-memset end
#define FLG_OFF    72000        // int[65536]
#define A1_OFF     137536       // u64[65536]     -- 0xFF-memset start
#define A2_OFF     268608       // u64[65536]     -- 0xFF-memset end
#define CBT_OFF    399680       // float[2048][256]
#define CBFH_OFF   923968       // f16 frag-order hi plane (1 MB)
#define CBFL_OFF   1186112      // f16 frag-order lo plane (1 MB)

typedef __attribute__((ext_vector_type(8))) _Float16 half8;
typedef __attribute__((ext_vector_type(4))) float f32x4;
typedef unsigned int u32;
typedef unsigned long long u64;

__device__ __forceinline__ void gl_lds16(const void* g, void* l) {
    __builtin_amdgcn_global_load_lds(
        (const __attribute__((address_space(1))) u32*)g,
        (__attribute__((address_space(3))) u32*)l, 16, 0, 0);
}

// ---------- ||e||^2 + biased half ----------
__global__ __launch_bounds__(256) void esq_k(const float* __restrict__ cb,
                                             float* __restrict__ esq,
                                             float* __restrict__ ebias) {
    int e = blockIdx.x * 256 + threadIdx.x;
    float s0 = 0.f, s1 = 0.f, s2 = 0.f, s3 = 0.f;
    for (int d = 0; d < EMB_DIM; d += 4) {
        float c0 = cb[(d + 0) * NUM_EMB + e];
        float c1 = cb[(d + 1) * NUM_EMB + e];
        float c2 = cb[(d + 2) * NUM_EMB + e];
        float c3 = cb[(d + 3) * NUM_EMB + e];
        s0 = fmaf(c0, c0, s0); s1 = fmaf(c1, c1, s1);
        s2 = fmaf(c2, c2, s2); s3 = fmaf(c3, c3, s3);
    }
    float s = (s0 + s1) + (s2 + s3);
    esq[e] = s;
    ebias[e] = DBIAS + 0.5f * s;
}

// ---------- transpose codebook: cbT fp32 + fragment-order f16 hi/lo planes ----------
// Frag layout (R3-proven): chunk (ct=col>>4, kt=k>>5, lane=lq*16+lm) holds col
// ct*16+lm, k=kt*32+lq*8..+8, at f16 index ((ct*8+kt)*64+lane)*8. Slice s of 8
// ct's => contiguous 64 KB region at byte offset s*65536.
__global__ __launch_bounds__(256) void prep_cbt(const float* __restrict__ cb,
                                                float* __restrict__ cbT,
                                                __half* __restrict__ cbFh,
                                                __half* __restrict__ cbFl) {
    __shared__ float lt[64][65];
    int t = threadIdx.x;
    int et = (blockIdx.x & 31) * 64;
    int dt = (blockIdx.x >> 5) * 64;
    #pragma unroll
    for (int p = 0; p < 4; ++p) {
        int d  = p * 16 + (t >> 4);
        int e4 = (t & 15) * 4;
        const float4 v = *(const float4*)&cb[(dt + d) * NUM_EMB + et + e4];
        lt[d][e4] = v.x; lt[d][e4 + 1] = v.y; lt[d][e4 + 2] = v.z; lt[d][e4 + 3] = v.w;
    }
    __syncthreads();
    #pragma unroll
    for (int p = 0; p < 4; ++p) {
        int e  = p * 16 + (t >> 4);
        int d4 = (t & 15) * 4;
        float4 v = make_float4(lt[d4][e], lt[d4 + 1][e], lt[d4 + 2][e], lt[d4 + 3][e]);
        *(float4*)&cbT[(size_t)(et + e) * EMB_DIM + dt + d4] = v;
    }
    #pragma unroll
    for (int q = 0; q < 2; ++q) {
        int cl = t * 2 + q;
        int col_l = cl >> 3, kc = cl & 7;
        int col = et + col_l;
        int kglob = dt + kc * 8;
        _Float16 hi[8], lo[8];
        #pragma unroll
        for (int j = 0; j < 8; ++j) {
            float v = lt[kc * 8 + j][col_l];
            __half h = __float2half(v);
            hi[j] = *(_Float16*)&h;
            __half l = __float2half(v - __half2float(h));
            lo[j] = *(_Float16*)&l;
        }
        int ct = col >> 4, lm = col & 15;
        int kt = kglob >> 5, lq = (kglob >> 3) & 3;
        size_t dst = ((size_t)(ct * 8 + kt) * 64 + lq * 16 + lm) * 8;
        *(half8*)&cbFh[dst] = *(half8*)hi;
        *(half8*)&cbFl[dst] = *(half8*)lo;
    }
}

// ---------- x -> fp16 hi/lo planes ([row][k] layout, in d_out scratch) ----------
__global__ __launch_bounds__(256) void prep_x(const float* __restrict__ x,
                                              __half* __restrict__ xh,
                                              __half* __restrict__ xl) {
    int t = threadIdx.x;
    int row = blockIdx.x * 4 + (t >> 6);
    int c = (t & 63) * 4;
    const float4 v = *(const float4*)&x[(size_t)row * EMB_DIM + c];
    float a[4] = {v.x, v.y, v.z, v.w};
    unsigned short hb[4], lb[4];
    #pragma unroll
    for (int i = 0; i < 4; ++i) {
        __half h = __float2half(a[i]);
        __half l = __float2half(a[i] - __half2float(h));
        hb[i] = __half_as_ushort(h); lb[i] = __half_as_ushort(l);
    }
    *(ushort4*)&xh[(size_t)row * EMB_DIM + c] = make_ushort4(hb[0], hb[1], hb[2], hb[3]);
    *(ushort4*)&xl[(size_t)row * EMB_DIM + c] = make_ushort4(lb[0], lb[1], lb[2], lb[3]);
}

// ---------- main: codebook-slice stationary in LDS, x streamed ----------
// Grid 1024 = 16 slices x 64 row-chunks (slice = bid&15 for temporal x locality).
// Block: 128 cols x K=256 hi+lo in 128 KB dynamic LDS (one barrier total).
// Wave: M=64 rows/pass (f=4), 4 passes of 256 rows. Per kt-round/CU: 384 MFMA
// (1862 cyc) vs 64 KB LDS + 32 KB global-A => MFMA-bound; A prefetched 1 kt ahead.
__global__ __launch_bounds__(256, 1) void argmin_slice(
    const __half* __restrict__ xh_, const __half* __restrict__ xl_,
    const __half* __restrict__ cbFh_, const __half* __restrict__ cbFl_,
    const float* __restrict__ ebias,
    u64* __restrict__ a1, u64* __restrict__ a2) {

    extern __shared__ char smem[];                // 131072 B
    _Float16* sBh = (_Float16*)smem;              // ((g*8+kt)*64+L)*8 halves
    _Float16* sBl = sBh + 32768;

    const int t = threadIdx.x;
    const int w = t >> 6, L = t & 63;
    const int lm = L & 15, lq = L >> 4;
    const int slice = blockIdx.x & 15;
    const int chunk = blockIdx.x >> 4;

    // ---- stage codebook slice (64 KB per plane = contiguous region) ----
    {
        const char* srcH = (const char*)cbFh_ + (size_t)slice * 65536;
        const char* srcL = (const char*)cbFl_ + (size_t)slice * 65536;
        #pragma unroll
        for (int i = 0; i < 16; ++i) {
            int byteoff = (i * 256 + t) * 16;     // lds base uniform: i*4096 + w*1024
            gl_lds16(srcH + byteoff, smem + (i * 4096 + w * 1024));
            gl_lds16(srcL + byteoff, smem + 65536 + (i * 4096 + w * 1024));
        }
    }
    __syncthreads();                              // the only barrier

    // per-lane ebias for the 8 col-groups
    float ebg[8];
    #pragma unroll
    for (int g = 0; g < 8; ++g) ebg[g] = ebias[slice * 128 + g * 16 + lm];

    const _Float16* xh = (const _Float16*)xh_;
    const _Float16* xl = (const _Float16*)xl_;
    const u32 STRIP = 0xFFFFFFF8u;

    // A prefetch for flat iteration it = pass*8 + kt
    half8 nah[4], nal[4];
    {
        int row0 = chunk * 1024 + 0 * 256 + w * 64 + lm;
        #pragma unroll
        for (int f = 0; f < 4; ++f) {
            size_t src = (size_t)(row0 + f * 16) * EMB_DIM + lq * 8;
            nah[f] = *(const half8*)&xh[src];
            nal[f] = *(const half8*)&xl[src];
        }
    }

    for (int pass = 0; pass < 4; ++pass) {
        const int rowbase = chunk * 1024 + pass * 256 + w * 64;
        f32x4 acc[4][8];
        #pragma unroll
        for (int f = 0; f < 4; ++f)
            #pragma unroll
            for (int g = 0; g < 8; ++g) acc[f][g] = (f32x4){0.f, 0.f, 0.f, 0.f};

        #pragma unroll
        for (int kt = 0; kt < 8; ++kt) {
            half8 ah[4], al[4];
            #pragma unroll
            for (int f = 0; f < 4; ++f) { ah[f] = nah[f]; al[f] = nal[f]; }
            int it = pass * 8 + kt + 1;
            if (it < 32) {                        // prefetch next kt (maybe next pass)
                int np = it >> 3, nk = it & 7;
                int row0 = chunk * 1024 + np * 256 + w * 64 + lm;
                #pragma unroll
                for (int f = 0; f < 4; ++f) {
                    size_t src = (size_t)(row0 + f * 16) * EMB_DIM + nk * 32 + lq * 8;
                    nah[f] = *(const half8*)&xh[src];
                    nal[f] = *(const half8*)&xl[src];
                }
            }
            #pragma unroll
            for (int g = 0; g < 8; ++g) {
                const half8 bh = *(const half8*)&sBh[((g * 8 + kt) * 64 + L) * 8];
                const half8 bl = *(const half8*)&sBl[((g * 8 + kt) * 64 + L) * 8];
                #pragma unroll
                for (int f = 0; f < 4; ++f) {
                    acc[f][g] = __builtin_amdgcn_mfma_f32_16x16x32_f16(ah[f], bh, acc[f][g], 0, 0, 0);
                    acc[f][g] = __builtin_amdgcn_mfma_f32_16x16x32_f16(ah[f], bl, acc[f][g], 0, 0, 0);
                    acc[f][g] = __builtin_amdgcn_mfma_f32_16x16x32_f16(al[f], bh, acc[f][g], 0, 0, 0);
                }
            }
        }

        // ---- epilogue: packed argmin (3-bit group id in mantissa), shuffle
        // reduce over the 16 col-lanes, exact-key u64 atomics ----
        #pragma unroll
        for (int f = 0; f < 4; ++f) {
            float m1[4], m2[4];
            #pragma unroll
            for (int r = 0; r < 4; ++r) { m1[r] = 3.4e38f; m2[r] = 3.4e38f; }
            #pragma unroll
            for (int g = 0; g < 8; ++g) {
                float eb = ebg[g];
                #pragma unroll
                for (int r = 0; r < 4; ++r) {
                    float d = eb - acc[f][g][r];
                    float dq = __uint_as_float((__float_as_uint(d) & STRIP) | (u32)g);
                    float hi = fmaxf(m1[r], dq);
                    m1[r] = fminf(m1[r], dq);
                    m2[r] = fminf(m2[r], hi);
                }
            }
            #pragma unroll
            for (int r = 0; r < 4; ++r) {
                float o1 = m1[r];
                float v1 = m1[r], v2 = m2[r];
                #pragma unroll
                for (int s = 1; s < 16; s <<= 1) {
                    float w1 = __shfl_xor(v1, s, 64);
                    float w2 = __shfl_xor(v2, s, 64);
                    v2 = fminf(fminf(v2, w2), fmaxf(v1, w1));
                    v1 = fminf(v1, w1);
                }
                u64 bal = __ballot(o1 == v1);
                int winl = __ffsll((unsigned long long)((bal >> (lq * 16)) & 0xFFFFull)) - 1;
                int gwin = (int)(__float_as_uint(v1) & 7u);
                int colw = slice * 128 + gwin * 16 + winl;
                if (lm == 0) {
                    int row = rowbase + f * 16 + lq * 4 + r;
                    u64 k1 = ((u64)(__float_as_uint(v1) & STRIP) << 32) | (u32)colw;
                    u64 old = atomicMin(&a1[row], k1);
                    u64 s2 = (k1 < old) ? old : k1;
                    atomicMin(&a2[row], s2);
                    u64 k2 = ((u64)(__float_as_uint(v2) & STRIP) << 32) | 0x7FFFFFFFull;
                    atomicMin(&a2[row], k2);
                }
            }
        }
    }
}

// ---------- per-row finalize: idx + EPS flagging ----------
__global__ __launch_bounds__(256) void reduce_rows(const u64* __restrict__ a1,
                                                   const u64* __restrict__ a2,
                                                   int* __restrict__ idx_out,
                                                   int* __restrict__ cnt,
                                                   int* __restrict__ flg) {
    int row = blockIdx.x * 256 + threadIdx.x;
    u64 v1 = a1[row], v2 = a2[row];
    idx_out[row] = (int)(v1 & 0xFFFFFFFFull);
    float d1 = __uint_as_float((u32)(v1 >> 32));
    float d2 = __uint_as_float((u32)(v2 >> 32));
    if (d2 - d1 < EPS_GAP) {
        int p = atomicAdd(cnt, 1);
        flg[p] = row;
    }
}

// ---------- exact fp32 re-check for flagged rows (R2/R3-proven) ----------
__global__ __launch_bounds__(256) void fallback_k(const float* __restrict__ x,
                                                  const float* __restrict__ cbT,
                                                  const float* __restrict__ esq,
                                                  const int* __restrict__ cnt,
                                                  const int* __restrict__ rows,
                                                  int* __restrict__ idx) {
    __shared__ float xr[256];
    __shared__ float sd[256];
    __shared__ int   si[256];
    __shared__ float sq[256];
    int t = threadIdx.x;
    int n = *cnt;
    for (int fi = blockIdx.x; fi < n; fi += gridDim.x) {
        int row = rows[fi];
        __syncthreads();
        float v = x[(size_t)row * EMB_DIM + t];
        xr[t] = v;
        sq[t] = v * v;
        __syncthreads();
        for (int stp = 128; stp > 0; stp >>= 1) {
            if (t < stp) sq[t] += sq[t + stp];
            __syncthreads();
        }
        float xq = sq[0];
        float bd = 3.4e38f; int bi = 0x7fffffff;
        for (int e = t; e < NUM_EMB; e += 256) {
            const float* cr = &cbT[(size_t)e * EMB_DIM];
            float s0 = 0.f, s1 = 0.f, s2 = 0.f, s3 = 0.f;
            for (int d = 0; d < EMB_DIM; d += 4) {
                const float4 c4 = *(const float4*)&cr[d];
                s0 = fmaf(xr[d], c4.x, s0);
                s1 = fmaf(xr[d + 1], c4.y, s1);
                s2 = fmaf(xr[d + 2], c4.z, s2);
                s3 = fmaf(xr[d + 3], c4.w, s3);
            }
            float sim = (s0 + s1) + (s2 + s3);
            float dd = (xq + esq[e]) - 2.0f * sim;
            if (dd < bd) { bd = dd; bi = e; }
        }
        sd[t] = bd; si[t] = bi;
        __syncthreads();
        for (int stp = 128; stp > 0; stp >>= 1) {
            if (t < stp) {
                if (sd[t + stp] < sd[t] || (sd[t + stp] == sd[t] && si[t + stp] < si[t])) {
                    sd[t] = sd[t + stp]; si[t] = si[t + stp];
                }
            }
            __syncthreads();
        }
        if (t == 0) idx[row] = si[0];
    }
}

// ---------- quantize + straight-through + loss partials + histogram ----------
__global__ __launch_bounds__(256) void quant_k(const float* __restrict__ x,
                                               const float* __restrict__ cbT,
                                               const int* __restrict__ idx,
                                               float* __restrict__ out,
                                               float* __restrict__ bkt,
                                               int* __restrict__ hist) {
    __shared__ float red[256];
    int t = threadIdx.x;
    int row = blockIdx.x * 16 + (t >> 4);
    int c0 = (t & 15) * 16;
    int e = idx[row];
    const float4* xp = (const float4*)&x[(size_t)row * EMB_DIM + c0];
    const float4* qp = (const float4*)&cbT[(size_t)e * EMB_DIM + c0];
    float4* op = (float4*)&out[(size_t)row * EMB_DIM + c0];
    float s = 0.f;
    #pragma unroll
    for (int j = 0; j < 4; ++j) {
        float4 xv = xp[j], qv = qp[j];
        float4 ov;
        ov.x = xv.x + (qv.x - xv.x); ov.y = xv.y + (qv.y - xv.y);
        ov.z = xv.z + (qv.z - xv.z); ov.w = xv.w + (qv.w - xv.w);
        op[j] = ov;
        float dx = xv.x - qv.x, dy = xv.y - qv.y, dz = xv.z - qv.z, dw = xv.w - qv.w;
        s += dx * dx + dy * dy + dz * dz + dw * dw;
    }
    red[t] = s;
    __syncthreads();
    for (int stp = 128; stp > 0; stp >>= 1) {
        if (t < stp) red[t] += red[t + stp];
        __syncthreads();
    }
    if (t == 0) atomicAdd(&bkt[blockIdx.x & 255], red[0]);
    if ((t & 15) == 0) atomicAdd(&hist[e], 1);
}

// ---------- finalize loss + perplexity ----------
__global__ __launch_bounds__(256) void final_k(const float* __restrict__ bkt,
                                               const int* __restrict__ hist,
                                               float* __restrict__ out) {
    int t = threadIdx.x;
    double ls = (double)bkt[t];
    double ps = 0.0;
    for (int i = t; i < NUM_EMB; i += 256) {
        double p = (double)hist[i] / (double)N_ROWS;
        ps += p * log(p + 1e-10);
    }
    __shared__ double sdd[256], spp[256];
    sdd[t] = ls; spp[t] = ps;
    __syncthreads();
    for (int s = 128; s > 0; s >>= 1) {
        if (t < s) { sdd[t] += sdd[t + s]; spp[t] += spp[t + s]; }
        __syncthreads();
    }
    if (t == 0) {
        out[N_ELEM + 0] = (float)(1.25 * sdd[0] / (double)N_ELEM);
        out[N_ELEM + 1] = (float)exp(-spp[0]);
    }
}

extern "C" void kernel_launch(void* const* d_in, const int* in_sizes, int n_in,
                              void* d_out, int out_size, void* d_ws, size_t ws_size,
                              hipStream_t stream) {
    const float* x  = (const float*)d_in[0];
    const float* cb = (const float*)d_in[1];
    float* out = (float*)d_out;

    float* ws_f = (float*)d_ws;
    int*   ws_i = (int*)d_ws;
    int*   idx   = ws_i + IDX_OFF;
    float* esq   = ws_f + ESQ_OFF;
    float* ebias = ws_f + EBIAS_OFF;
    int*   hist  = ws_i + HIST_OFF;
    float* bkt   = ws_f + BKT_OFF;
    int*   cnt   = ws_i + CNT_OFF;
    int*   flg   = ws_i + FLG_OFF;
    u64*   a1    = (u64*)(ws_f + A1_OFF);
    u64*   a2    = (u64*)(ws_f + A2_OFF);
    float* cbT   = ws_f + CBT_OFF;
    __half* cbFh = (__half*)(ws_f + CBFH_OFF);
    __half* cbFl = (__half*)(ws_f + CBFL_OFF);

    __half* xh = (__half*)d_out;
    __half* xl = (__half*)((char*)d_out + (size_t)N_ELEM * 2);

    hipMemsetAsync((char*)d_ws + (size_t)HIST_OFF * 4, 0,
                   (size_t)(CNT_OFF + 64 - HIST_OFF) * 4, stream);
    hipMemsetAsync((char*)d_ws + (size_t)A1_OFF * 4, 0xFF,
                   (size_t)(N_ROWS * 2) * 8, stream);

    esq_k<<<NUM_EMB / 256, 256, 0, stream>>>(cb, esq, ebias);
    prep_cbt<<<128, 256, 0, stream>>>(cb, cbT, cbFh, cbFl);
    prep_x<<<N_ROWS / 4, 256, 0, stream>>>(x, xh, xl);

    hipFuncSetAttribute((const void*)argmin_slice,
                        hipFuncAttributeMaxDynamicSharedMemorySize, 131072);
    argmin_slice<<<1024, 256, 131072, stream>>>(xh, xl, cbFh, cbFl, ebias, a1, a2);

    reduce_rows<<<N_ROWS / 256, 256, 0, stream>>>(a1, a2, idx, cnt, flg);
    fallback_k<<<1024, 256, 0, stream>>>(x, cbT, esq, cnt, flg, idx);
    quant_k<<<N_ROWS / 16, 256, 0, stream>>>(x, cbT, idx, out, bkt, hist);
    final_k<<<1, 256, 0, stream>>>(bkt, hist, out);
}